// Round 1
// baseline (3175.072 us; speedup 1.0000x reference)
//
#include <hip/hip_runtime.h>
#include <math.h>

// Shapes (fixed by the problem): B=4, C=512, H=W=64 -> HW=4096
constexpr int BATCH = 4;
constexpr int CH    = 512;
constexpr int HWDIM = 4096;
constexpr long CN   = (long)CH * HWDIM;      // 2,097,152 elems per batch
constexpr int GSIZE = 65536;                 // elems per group: 16 ch * 4096
constexpr float GN_EPS = 1e-5f;

// ---------------- GroupNorm: per-(batch,group) stats ----------------
__global__ void gn_stats_kernel(const float* __restrict__ x,
                                float* __restrict__ mu, float* __restrict__ rs) {
  const int grp = blockIdx.x;                // 0..127 = b*32+g (groups are contiguous 65536-chunks)
  const float4* p = (const float4*)(x + (long)grp * GSIZE);
  float s = 0.f, q = 0.f;
  for (int i = threadIdx.x; i < GSIZE / 4; i += 256) {
    float4 v = p[i];
    s += (v.x + v.y) + (v.z + v.w);
    q += (v.x * v.x + v.y * v.y) + (v.z * v.z + v.w * v.w);
  }
  #pragma unroll
  for (int o = 32; o > 0; o >>= 1) {
    s += __shfl_xor(s, o, 64);
    q += __shfl_xor(q, o, 64);
  }
  __shared__ float ls[4], lq[4];
  if ((threadIdx.x & 63) == 0) { ls[threadIdx.x >> 6] = s; lq[threadIdx.x >> 6] = q; }
  __syncthreads();
  if (threadIdx.x == 0) {
    float S = (ls[0] + ls[1]) + (ls[2] + ls[3]);
    float Q = (lq[0] + lq[1]) + (lq[2] + lq[3]);
    float m = S * (1.f / GSIZE);
    float var = Q * (1.f / GSIZE) - m * m;
    mu[grp] = m;
    rs[grp] = rsqrtf(var + GN_EPS);
  }
}

// ---------------- GroupNorm: normalize + affine ----------------
__global__ void gn_norm_kernel(const float* __restrict__ x,
                               const float* __restrict__ mu, const float* __restrict__ rs,
                               const float* __restrict__ gw, const float* __restrict__ gb,
                               float* __restrict__ h) {
  long i = ((long)blockIdx.x * 256 + threadIdx.x) * 4;   // global flat float index
  int c   = (int)((i >> 12) & 511);   // channel (HW=4096=2^12; all 4 lanes of float4 same c)
  int grp = (int)(i >> 16);           // global group id (65536 elems per group)
  float m = mu[grp], r = rs[grp];
  float w = gw[c] * r;
  float bia = gb[c] - m * w;
  float4 v = *(const float4*)(x + i);
  v.x = v.x * w + bia;
  v.y = v.y * w + bia;
  v.z = v.z * w + bia;
  v.w = v.w * w + bia;
  *(float4*)(h + i) = v;
}

// ---------------- Generic fp32 tiled GEMM ----------------
// Cm[m,n] = sum_k Aval(m,k)*Bval(n,k) (+bias[n]) (+res[m*ldc+n])
//   Aval(m,k) = AKC ? A[m*lda+k] : A[k*lda+m]
//   Bval(n,k) = BKC ? B[n*ldb+k] : B[k*ldb+n]
// BM=BN=128, BK=16, 256 threads, 8x8 micro-tile (2x2 quadrants of 4x4).
// All M,N multiples of 128 and K multiples of 16 in this problem -> no bounds checks.
template<bool AKC, bool BKC, bool HASBIAS, bool HASRES>
__launch_bounds__(256, 2)
__global__ void gemm_f32(const float* __restrict__ A, const float* __restrict__ Bm,
                         const float* __restrict__ bias, const float* __restrict__ res,
                         float* __restrict__ Cm,
                         int lda, int ldb, int ldc, int K) {
  constexpr int BK = 16;
  __shared__ float As[BK][132];   // +4 pad: transposed staging writes land 2-way max (free)
  __shared__ float Bs[BK][132];
  const int m0 = blockIdx.x * 128;
  const int n0 = blockIdx.y * 128;
  const int t  = threadIdx.x;
  const int tx = t & 15, ty = t >> 4;

  float acc[8][8];
  #pragma unroll
  for (int i = 0; i < 8; i++)
    #pragma unroll
    for (int j = 0; j < 8; j++) acc[i][j] = 0.f;

  for (int k0 = 0; k0 < K; k0 += BK) {
    #pragma unroll
    for (int ch = 0; ch < 2; ch++) {
      int id = t + ch * 256;                 // 512 float4-chunks per tile pair
      if (AKC) {
        int row = id >> 2, kc = (id & 3) * 4;
        float4 v = *(const float4*)(A + (long)(m0 + row) * lda + (k0 + kc));
        As[kc + 0][row] = v.x; As[kc + 1][row] = v.y;
        As[kc + 2][row] = v.z; As[kc + 3][row] = v.w;
      } else {
        int kk = id >> 5, mm = (id & 31) * 4;
        *(float4*)&As[kk][mm] = *(const float4*)(A + (long)(k0 + kk) * lda + (m0 + mm));
      }
      if (BKC) {
        int row = id >> 2, kc = (id & 3) * 4;
        float4 v = *(const float4*)(Bm + (long)(n0 + row) * ldb + (k0 + kc));
        Bs[kc + 0][row] = v.x; Bs[kc + 1][row] = v.y;
        Bs[kc + 2][row] = v.z; Bs[kc + 3][row] = v.w;
      } else {
        int kk = id >> 5, nn = (id & 31) * 4;
        *(float4*)&Bs[kk][nn] = *(const float4*)(Bm + (long)(k0 + kk) * ldb + (n0 + nn));
      }
    }
    __syncthreads();
    #pragma unroll
    for (int kk = 0; kk < BK; kk++) {
      float a[8], b[8];
      *(float4*)(a + 0) = *(const float4*)&As[kk][ty * 4];
      *(float4*)(a + 4) = *(const float4*)&As[kk][64 + ty * 4];
      *(float4*)(b + 0) = *(const float4*)&Bs[kk][tx * 4];
      *(float4*)(b + 4) = *(const float4*)&Bs[kk][64 + tx * 4];
      #pragma unroll
      for (int i = 0; i < 8; i++)
        #pragma unroll
        for (int j = 0; j < 8; j++)
          acc[i][j] = fmaf(a[i], b[j], acc[i][j]);
    }
    __syncthreads();
  }

  float4 blo = {0.f,0.f,0.f,0.f}, bhi = {0.f,0.f,0.f,0.f};
  if (HASBIAS) {
    blo = *(const float4*)(bias + n0 + tx * 4);
    bhi = *(const float4*)(bias + n0 + 64 + tx * 4);
  }
  #pragma unroll
  for (int i = 0; i < 8; i++) {
    int mloc = (i < 4) ? (ty * 4 + i) : (64 + ty * 4 + (i - 4));
    long base = (long)(m0 + mloc) * ldc + n0;
    float4 lo, hi;
    lo.x = acc[i][0] + blo.x; lo.y = acc[i][1] + blo.y;
    lo.z = acc[i][2] + blo.z; lo.w = acc[i][3] + blo.w;
    hi.x = acc[i][4] + bhi.x; hi.y = acc[i][5] + bhi.y;
    hi.z = acc[i][6] + bhi.z; hi.w = acc[i][7] + bhi.w;
    if (HASRES) {
      float4 r0 = *(const float4*)(res + base + tx * 4);
      float4 r1 = *(const float4*)(res + base + 64 + tx * 4);
      lo.x += r0.x; lo.y += r0.y; lo.z += r0.z; lo.w += r0.w;
      hi.x += r1.x; hi.y += r1.y; hi.z += r1.z; hi.w += r1.w;
    }
    *(float4*)(Cm + base + tx * 4)      = lo;
    *(float4*)(Cm + base + 64 + tx * 4) = hi;
  }
}

// ---------------- Row softmax over attn (4096 floats per row) ----------------
__global__ void softmax_kernel(float* __restrict__ attn) {
  float* p = attn + (long)blockIdx.x * HWDIM;
  const int t = threadIdx.x;                 // 256 threads, 16 floats each in regs
  float4 v[4];
  float mx = -1e30f;
  #pragma unroll
  for (int u = 0; u < 4; u++) {
    v[u] = ((const float4*)p)[t + u * 256];
    mx = fmaxf(mx, fmaxf(fmaxf(v[u].x, v[u].y), fmaxf(v[u].z, v[u].w)));
  }
  #pragma unroll
  for (int o = 32; o > 0; o >>= 1) mx = fmaxf(mx, __shfl_xor(mx, o, 64));
  __shared__ float rmax[4], rsum[4];
  if ((t & 63) == 0) rmax[t >> 6] = mx;
  __syncthreads();
  mx = fmaxf(fmaxf(rmax[0], rmax[1]), fmaxf(rmax[2], rmax[3]));
  float s = 0.f;
  #pragma unroll
  for (int u = 0; u < 4; u++) {
    v[u].x = __expf(v[u].x - mx); v[u].y = __expf(v[u].y - mx);
    v[u].z = __expf(v[u].z - mx); v[u].w = __expf(v[u].w - mx);
    s += (v[u].x + v[u].y) + (v[u].z + v[u].w);
  }
  #pragma unroll
  for (int o = 32; o > 0; o >>= 1) s += __shfl_xor(s, o, 64);
  if ((t & 63) == 0) rsum[t >> 6] = s;
  __syncthreads();
  s = (rsum[0] + rsum[1]) + (rsum[2] + rsum[3]);
  float inv = 1.f / s;
  #pragma unroll
  for (int u = 0; u < 4; u++) {
    v[u].x *= inv; v[u].y *= inv; v[u].z *= inv; v[u].w *= inv;
    ((float4*)p)[t + u * 256] = v[u];
  }
}

// ---------------- launch ----------------
extern "C" void kernel_launch(void* const* d_in, const int* in_sizes, int n_in,
                              void* d_out, int out_size, void* d_ws, size_t ws_size,
                              hipStream_t stream) {
  (void)in_sizes; (void)n_in; (void)out_size; (void)ws_size;
  const float* x  = (const float*)d_in[0];
  const float* gw = (const float*)d_in[1];
  const float* gb = (const float*)d_in[2];
  const float* wq = (const float*)d_in[3];
  const float* bq = (const float*)d_in[4];
  const float* wk = (const float*)d_in[5];
  const float* bk = (const float*)d_in[6];
  const float* wv = (const float*)d_in[7];
  const float* bv = (const float*)d_in[8];
  const float* wo = (const float*)d_in[9];
  const float* bo = (const float*)d_in[10];
  float* out = (float*)d_out;
  float* ws  = (float*)d_ws;

  // Workspace layout (needs 160 MB + 1 KB):
  //   [attn: 16,777,216 f][q: 8,388,608 f][k: 8,388,608 f][v: 8,388,608 f][mu:128][rs:128]
  // h (8,388,608 f) aliases the start of attn: h is dead before the first attn GEMM writes.
  // ot_b overwrites q_b: q_b is dead after batch b's QK^T GEMM.
  float* attn = ws;
  float* h    = ws;
  float* q    = ws + 16777216;
  float* kbuf = q + 8388608;
  float* vbuf = kbuf + 8388608;
  float* mu   = vbuf + 8388608;
  float* rs   = mu + 128;

  gn_stats_kernel<<<dim3(128), dim3(256), 0, stream>>>(x, mu, rs);
  gn_norm_kernel<<<dim3(8192), dim3(256), 0, stream>>>(x, mu, rs, gw, gb, h);

  // QKV projections: (16384 x 512) = (16384 x 512) @ W^T, all batches at once
  dim3 gproj(128, 4);
  gemm_f32<true,true,true,false><<<gproj, 256, 0, stream>>>(h, wq, bq, nullptr, q,    512, 512, 512, 512);
  gemm_f32<true,true,true,false><<<gproj, 256, 0, stream>>>(h, wk, bk, nullptr, kbuf, 512, 512, 512, 512);
  gemm_f32<true,true,true,false><<<gproj, 256, 0, stream>>>(h, wv, bv, nullptr, vbuf, 512, 512, 512, 512);

  dim3 gattn(32, 32);  // 4096 x 4096
  dim3 gout(32, 4);    // 4096 x 512
  for (int b = 0; b < BATCH; b++) {
    const float* qb = q    + (long)b * CN;
    const float* kb = kbuf + (long)b * CN;
    const float* vb = vbuf + (long)b * CN;
    float* otb = q + (long)b * CN;  // reuse q_b region for ot_b
    // attn[n,m] = sum_c qb[c*4096+n] * kb[c*4096+m]
    gemm_f32<false,false,false,false><<<gattn, 256, 0, stream>>>(qb, kb, nullptr, nullptr, attn, 4096, 4096, 4096, 512);
    softmax_kernel<<<dim3(4096), dim3(256), 0, stream>>>(attn);
    // ot[n,c] = sum_m attn[n*4096+m] * vb[c*4096+m]
    gemm_f32<true,true,false,false><<<gout, 256, 0, stream>>>(attn, vb, nullptr, nullptr, otb, 4096, 4096, 512, 4096);
  }
  // out[n,j] = sum_c ot[n*512+c]*wo[j*512+c] + bo[j] + x_flat[n*512+j]  (flat residual)
  gemm_f32<true,true,true,true><<<gproj, 256, 0, stream>>>(q, wo, bo, x, out, 512, 512, 512, 512);
}

// Round 2
// 1642.170 us; speedup vs baseline: 1.9335x; 1.9335x over previous
//
#include <hip/hip_runtime.h>
#include <math.h>

// Shapes (fixed by the problem): B=4, C=512, H=W=64 -> HW=4096
constexpr int BATCH = 4;
constexpr int CH    = 512;
constexpr int HWDIM = 4096;
constexpr long CN   = (long)CH * HWDIM;      // 2,097,152 elems per batch
constexpr int GSIZE = 65536;                 // elems per group: 16 ch * 4096
constexpr float GN_EPS = 1e-5f;

typedef __attribute__((ext_vector_type(8))) short bf16x8;
typedef __attribute__((ext_vector_type(4))) float f32x4;

// ---------------- GroupNorm: per-(batch,group) stats ----------------
__global__ void gn_stats_kernel(const float* __restrict__ x,
                                float* __restrict__ mu, float* __restrict__ rs) {
  const int grp = blockIdx.x;                // 0..127 = b*32+g
  const float4* p = (const float4*)(x + (long)grp * GSIZE);
  float s = 0.f, q = 0.f;
  for (int i = threadIdx.x; i < GSIZE / 4; i += 256) {
    float4 v = p[i];
    s += (v.x + v.y) + (v.z + v.w);
    q += (v.x * v.x + v.y * v.y) + (v.z * v.z + v.w * v.w);
  }
  #pragma unroll
  for (int o = 32; o > 0; o >>= 1) {
    s += __shfl_xor(s, o, 64);
    q += __shfl_xor(q, o, 64);
  }
  __shared__ float ls[4], lq[4];
  if ((threadIdx.x & 63) == 0) { ls[threadIdx.x >> 6] = s; lq[threadIdx.x >> 6] = q; }
  __syncthreads();
  if (threadIdx.x == 0) {
    float S = (ls[0] + ls[1]) + (ls[2] + ls[3]);
    float Q = (lq[0] + lq[1]) + (lq[2] + lq[3]);
    float m = S * (1.f / GSIZE);
    float var = Q * (1.f / GSIZE) - m * m;
    mu[grp] = m;
    rs[grp] = rsqrtf(var + GN_EPS);
  }
}

// ---------------- GroupNorm: normalize + affine ----------------
__global__ void gn_norm_kernel(const float* __restrict__ x,
                               const float* __restrict__ mu, const float* __restrict__ rs,
                               const float* __restrict__ gw, const float* __restrict__ gb,
                               float* __restrict__ h) {
  long i = ((long)blockIdx.x * 256 + threadIdx.x) * 4;
  int c   = (int)((i >> 12) & 511);
  int grp = (int)(i >> 16);
  float m = mu[grp], r = rs[grp];
  float w = gw[c] * r;
  float bia = gb[c] - m * w;
  float4 v = *(const float4*)(x + i);
  v.x = v.x * w + bia;
  v.y = v.y * w + bia;
  v.z = v.z * w + bia;
  v.w = v.w * w + bia;
  *(float4*)(h + i) = v;
}

// ---------------- Generic fp32 tiled GEMM (unchanged from R1) ----------------
template<bool AKC, bool BKC, bool HASBIAS, bool HASRES>
__launch_bounds__(256, 2)
__global__ void gemm_f32(const float* __restrict__ A, const float* __restrict__ Bm,
                         const float* __restrict__ bias, const float* __restrict__ res,
                         float* __restrict__ Cm,
                         int lda, int ldb, int ldc, int K) {
  constexpr int BK = 16;
  __shared__ float As[BK][132];
  __shared__ float Bs[BK][132];
  const int m0 = blockIdx.x * 128;
  const int n0 = blockIdx.y * 128;
  const int t  = threadIdx.x;
  const int tx = t & 15, ty = t >> 4;

  float acc[8][8];
  #pragma unroll
  for (int i = 0; i < 8; i++)
    #pragma unroll
    for (int j = 0; j < 8; j++) acc[i][j] = 0.f;

  for (int k0 = 0; k0 < K; k0 += BK) {
    #pragma unroll
    for (int ch = 0; ch < 2; ch++) {
      int id = t + ch * 256;
      if (AKC) {
        int row = id >> 2, kc = (id & 3) * 4;
        float4 v = *(const float4*)(A + (long)(m0 + row) * lda + (k0 + kc));
        As[kc + 0][row] = v.x; As[kc + 1][row] = v.y;
        As[kc + 2][row] = v.z; As[kc + 3][row] = v.w;
      } else {
        int kk = id >> 5, mm = (id & 31) * 4;
        *(float4*)&As[kk][mm] = *(const float4*)(A + (long)(k0 + kk) * lda + (m0 + mm));
      }
      if (BKC) {
        int row = id >> 2, kc = (id & 3) * 4;
        float4 v = *(const float4*)(Bm + (long)(n0 + row) * ldb + (k0 + kc));
        Bs[kc + 0][row] = v.x; Bs[kc + 1][row] = v.y;
        Bs[kc + 2][row] = v.z; Bs[kc + 3][row] = v.w;
      } else {
        int kk = id >> 5, nn = (id & 31) * 4;
        *(float4*)&Bs[kk][nn] = *(const float4*)(Bm + (long)(k0 + kk) * ldb + (n0 + nn));
      }
    }
    __syncthreads();
    #pragma unroll
    for (int kk = 0; kk < BK; kk++) {
      float a[8], b[8];
      *(float4*)(a + 0) = *(const float4*)&As[kk][ty * 4];
      *(float4*)(a + 4) = *(const float4*)&As[kk][64 + ty * 4];
      *(float4*)(b + 0) = *(const float4*)&Bs[kk][tx * 4];
      *(float4*)(b + 4) = *(const float4*)&Bs[kk][64 + tx * 4];
      #pragma unroll
      for (int i = 0; i < 8; i++)
        #pragma unroll
        for (int j = 0; j < 8; j++)
          acc[i][j] = fmaf(a[i], b[j], acc[i][j]);
    }
    __syncthreads();
  }

  float4 blo = {0.f,0.f,0.f,0.f}, bhi = {0.f,0.f,0.f,0.f};
  if (HASBIAS) {
    blo = *(const float4*)(bias + n0 + tx * 4);
    bhi = *(const float4*)(bias + n0 + 64 + tx * 4);
  }
  #pragma unroll
  for (int i = 0; i < 8; i++) {
    int mloc = (i < 4) ? (ty * 4 + i) : (64 + ty * 4 + (i - 4));
    long base = (long)(m0 + mloc) * ldc + n0;
    float4 lo, hi;
    lo.x = acc[i][0] + blo.x; lo.y = acc[i][1] + blo.y;
    lo.z = acc[i][2] + blo.z; lo.w = acc[i][3] + blo.w;
    hi.x = acc[i][4] + bhi.x; hi.y = acc[i][5] + bhi.y;
    hi.z = acc[i][6] + bhi.z; hi.w = acc[i][7] + bhi.w;
    if (HASRES) {
      float4 r0 = *(const float4*)(res + base + tx * 4);
      float4 r1 = *(const float4*)(res + base + 64 + tx * 4);
      lo.x += r0.x; lo.y += r0.y; lo.z += r0.z; lo.w += r0.w;
      hi.x += r1.x; hi.y += r1.y; hi.z += r1.z; hi.w += r1.w;
    }
    *(float4*)(Cm + base + tx * 4)      = lo;
    *(float4*)(Cm + base + 64 + tx * 4) = hi;
  }
}

// ---------------- Row softmax over attn (4096 floats per row) ----------------
__global__ void softmax_kernel(float* __restrict__ attn) {
  float* p = attn + (long)blockIdx.x * HWDIM;
  const int t = threadIdx.x;
  float4 v[4];
  float mx = -1e30f;
  #pragma unroll
  for (int u = 0; u < 4; u++) {
    v[u] = ((const float4*)p)[t + u * 256];
    mx = fmaxf(mx, fmaxf(fmaxf(v[u].x, v[u].y), fmaxf(v[u].z, v[u].w)));
  }
  #pragma unroll
  for (int o = 32; o > 0; o >>= 1) mx = fmaxf(mx, __shfl_xor(mx, o, 64));
  __shared__ float rmax[4], rsum[4];
  if ((t & 63) == 0) rmax[t >> 6] = mx;
  __syncthreads();
  mx = fmaxf(fmaxf(rmax[0], rmax[1]), fmaxf(rmax[2], rmax[3]));
  float s = 0.f;
  #pragma unroll
  for (int u = 0; u < 4; u++) {
    v[u].x = __expf(v[u].x - mx); v[u].y = __expf(v[u].y - mx);
    v[u].z = __expf(v[u].z - mx); v[u].w = __expf(v[u].w - mx);
    s += (v[u].x + v[u].y) + (v[u].z + v[u].w);
  }
  #pragma unroll
  for (int o = 32; o > 0; o >>= 1) s += __shfl_xor(s, o, 64);
  if ((t & 63) == 0) rsum[t >> 6] = s;
  __syncthreads();
  s = (rsum[0] + rsum[1]) + (rsum[2] + rsum[3]);
  float inv = 1.f / s;
  #pragma unroll
  for (int u = 0; u < 4; u++) {
    v[u].x *= inv; v[u].y *= inv; v[u].z *= inv; v[u].w *= inv;
    ((float4*)p)[t + u * 256] = v[u];
  }
}

// ---------------- PV via bf16 MFMA ----------------
// Pout[n,c] = sum_{m in z-half} P[n,m] * V[c,m]
// P: (4096 x 4096) f32 row-major (k=m contiguous). V: (512 x 4096) f32 row-major.
// Tile 128(M=n) x 128(N=c) x BK=64; 4 waves in 2x2 quadrants of 64x64;
// 16x16x32 bf16 mfma. LDS is LANE-MAJOR fragment order: frag reads are
// addr = base + lane*16B (conflict-free); staging writes are 2-way max (free).
// grid (32, 4, 2): z = K-half -> partials into out0/out1, reduced afterwards.
__device__ __forceinline__ unsigned pk2bf(float a, float b) {
  // round-half-up bf16 pack: a -> low short, b -> high short
  union { float f; unsigned u; } x, y; x.f = a; y.f = b;
  return ((x.u + 0x8000u) >> 16) | ((y.u + 0x8000u) & 0xFFFF0000u);
}

__launch_bounds__(256)
__global__ void pv_mfma(const float* __restrict__ P, const float* __restrict__ V,
                        float* __restrict__ out0, float* __restrict__ out1) {
  // [mtile(8)][kk32(2)][lane(64)][8 shorts]
  __shared__ short As[8192];
  __shared__ short Bs[8192];
  const int n0 = blockIdx.x * 128;
  const int c0 = blockIdx.y * 128;
  const long kbase = (long)blockIdx.z * 2048;
  float* __restrict__ Pout = blockIdx.z ? out1 : out0;
  const int t = threadIdx.x;
  const int lane = t & 63;
  const int w = t >> 6;
  const int wm = w & 1, wn = w >> 1;

  // staging assignment: thread covers (row = t>>2 [+64], kgrp = t&3 [+4*..])
  const int srow = t >> 2;   // 0..63
  const int skg  = t & 3;

  f32x4 acc[4][4];
  #pragma unroll
  for (int i = 0; i < 4; i++)
    #pragma unroll
    for (int j = 0; j < 4; j++) acc[i][j] = (f32x4){0.f, 0.f, 0.f, 0.f};

  float4 av[8], bv[8];
  #pragma unroll
  for (int it = 0; it < 8; it++) {
    int row = srow + 64 * (it & 1);
    int kg  = skg + 4 * (it >> 1);
    av[it] = *(const float4*)(P + (long)(n0 + row) * 4096 + kbase + kg * 4);
    bv[it] = *(const float4*)(V + (long)(c0 + row) * 4096 + kbase + kg * 4);
  }

  for (int k0 = 0; k0 < 2048; k0 += 64) {
    __syncthreads();   // previous compute done; LDS reusable
    #pragma unroll
    for (int it = 0; it < 8; it++) {
      int row = srow + 64 * (it & 1);
      int kg  = skg + 4 * (it >> 1);
      // slot: ((row/16)*2 + kg/8)*64 + (row%16) + ((kg/2)%4)*16, 8 shorts each,
      //       plus (kg&1)*4 within the 8-short group
      int slot = ((((row >> 4) * 2 + (kg >> 3)) * 64 + (row & 15) + ((kg >> 1) & 3) * 16) << 3)
               + (kg & 1) * 4;
      uint2 pa = { pk2bf(av[it].x, av[it].y), pk2bf(av[it].z, av[it].w) };
      uint2 pb = { pk2bf(bv[it].x, bv[it].y), pk2bf(bv[it].z, bv[it].w) };
      *(uint2*)&As[slot] = pa;
      *(uint2*)&Bs[slot] = pb;
    }
    if (k0 + 64 < 2048) {   // register prefetch of next k-tile overlaps MFMA phase
      #pragma unroll
      for (int it = 0; it < 8; it++) {
        int row = srow + 64 * (it & 1);
        int kg  = skg + 4 * (it >> 1);
        av[it] = *(const float4*)(P + (long)(n0 + row) * 4096 + kbase + k0 + 64 + kg * 4);
        bv[it] = *(const float4*)(V + (long)(c0 + row) * 4096 + kbase + k0 + 64 + kg * 4);
      }
    }
    __syncthreads();   // LDS tile ready
    #pragma unroll
    for (int kk = 0; kk < 2; kk++) {
      bf16x8 a[4], b[4];
      #pragma unroll
      for (int i = 0; i < 4; i++)
        a[i] = *(const bf16x8*)&As[((((wm * 4 + i) * 2 + kk) * 64 + lane) << 3)];
      #pragma unroll
      for (int j = 0; j < 4; j++)
        b[j] = *(const bf16x8*)&Bs[((((wn * 4 + j) * 2 + kk) * 64 + lane) << 3)];
      #pragma unroll
      for (int i = 0; i < 4; i++)
        #pragma unroll
        for (int j = 0; j < 4; j++)
          acc[i][j] = __builtin_amdgcn_mfma_f32_16x16x32_bf16(a[i], b[j], acc[i][j], 0, 0, 0);
    }
  }

  // store: D layout col = lane&15, row = (lane>>4)*4 + r
  const int lm = lane & 15, quad = lane >> 4;
  #pragma unroll
  for (int i = 0; i < 4; i++) {
    #pragma unroll
    for (int j = 0; j < 4; j++) {
      int nn = n0 + wm * 64 + i * 16 + quad * 4;
      int cc = c0 + wn * 64 + j * 16 + lm;
      #pragma unroll
      for (int r = 0; r < 4; r++)
        Pout[(long)(nn + r) * 512 + cc] = acc[i][j][r];
    }
  }
}

// ---------------- a += b (split-K reduce) ----------------
__global__ void add2_kernel(float* __restrict__ a, const float* __restrict__ b) {
  long i = ((long)blockIdx.x * 256 + threadIdx.x) * 4;
  float4 va = *(float4*)(a + i);
  float4 vb = *(const float4*)(b + i);
  va.x += vb.x; va.y += vb.y; va.z += vb.z; va.w += vb.w;
  *(float4*)(a + i) = va;
}

// ---------------- launch ----------------
extern "C" void kernel_launch(void* const* d_in, const int* in_sizes, int n_in,
                              void* d_out, int out_size, void* d_ws, size_t ws_size,
                              hipStream_t stream) {
  (void)in_sizes; (void)n_in; (void)out_size; (void)ws_size;
  const float* x  = (const float*)d_in[0];
  const float* gw = (const float*)d_in[1];
  const float* gb = (const float*)d_in[2];
  const float* wq = (const float*)d_in[3];
  const float* bq = (const float*)d_in[4];
  const float* wk = (const float*)d_in[5];
  const float* bk = (const float*)d_in[6];
  const float* wv = (const float*)d_in[7];
  const float* bv = (const float*)d_in[8];
  const float* wo = (const float*)d_in[9];
  const float* bo = (const float*)d_in[10];
  float* out = (float*)d_out;
  float* ws  = (float*)d_ws;

  // Workspace (160 MB + 1 KB):
  //   [attn: 16,777,216 f][q: 8,388,608 f][k: 8,388,608 f][v: 8,388,608 f][mu:128][rs:128]
  // h aliases attn (dead before first QK^T write).
  // Per batch b: after QK^T(b), q_b and k_b are dead -> PV split-K partials
  // go to q_b (z=0) and k_b (z=1); reduce writes ot_b into q_b.
  float* attn = ws;
  float* h    = ws;
  float* q    = ws + 16777216;
  float* kbuf = q + 8388608;
  float* vbuf = kbuf + 8388608;
  float* mu   = vbuf + 8388608;
  float* rs   = mu + 128;

  gn_stats_kernel<<<dim3(128), dim3(256), 0, stream>>>(x, mu, rs);
  gn_norm_kernel<<<dim3(8192), dim3(256), 0, stream>>>(x, mu, rs, gw, gb, h);

  dim3 gproj(128, 4);
  gemm_f32<true,true,true,false><<<gproj, 256, 0, stream>>>(h, wq, bq, nullptr, q,    512, 512, 512, 512);
  gemm_f32<true,true,true,false><<<gproj, 256, 0, stream>>>(h, wk, bk, nullptr, kbuf, 512, 512, 512, 512);
  gemm_f32<true,true,true,false><<<gproj, 256, 0, stream>>>(h, wv, bv, nullptr, vbuf, 512, 512, 512, 512);

  dim3 gattn(32, 32);
  for (int b = 0; b < BATCH; b++) {
    const float* qb = q    + (long)b * CN;
    float*       kb = kbuf + (long)b * CN;
    const float* vb = vbuf + (long)b * CN;
    float* otb = q + (long)b * CN;
    gemm_f32<false,false,false,false><<<gattn, 256, 0, stream>>>(qb, kb, nullptr, nullptr, attn, 4096, 4096, 4096, 512);
    softmax_kernel<<<dim3(4096), dim3(256), 0, stream>>>(attn);
    pv_mfma<<<dim3(32, 4, 2), 256, 0, stream>>>(attn, vb, otb, kb);
    add2_kernel<<<dim3(2048), 256, 0, stream>>>(otb, kb);
  }
  gemm_f32<true,true,true,true><<<gproj, 256, 0, stream>>>(q, wo, bo, x, out, 512, 512, 512, 512);
}

// Round 3
// 970.047 us; speedup vs baseline: 3.2731x; 1.6929x over previous
//
#include <hip/hip_runtime.h>
#include <math.h>

// Shapes (fixed): B=4, C=512, H=W=64 -> HW=4096
constexpr int BATCH = 4;
constexpr int HWDIM = 4096;
constexpr long CN   = 2097152;               // 512*4096 elems per batch
constexpr int GSIZE = 65536;
constexpr float GN_EPS = 1e-5f;

typedef __attribute__((ext_vector_type(8))) short bf16x8;
typedef __attribute__((ext_vector_type(4))) float f32x4;

__device__ __forceinline__ unsigned pk2bf(float a, float b) {
  union { float f; unsigned u; } x{a}, y{b};
  return ((x.u + 0x8000u) >> 16) | ((y.u + 0x8000u) & 0xFFFF0000u);
}
// split float4 -> bf16 hi (round-half-up) + bf16 lo (residual), packed pairs
__device__ __forceinline__ void split4(const float4 v, uint2& hi, uint2& lo) {
  union { float f; unsigned u; } a{v.x}, b{v.y}, c{v.z}, d{v.w};
  unsigned ha = (a.u + 0x8000u) & 0xFFFF0000u;
  unsigned hb = (b.u + 0x8000u) & 0xFFFF0000u;
  unsigned hc = (c.u + 0x8000u) & 0xFFFF0000u;
  unsigned hd = (d.u + 0x8000u) & 0xFFFF0000u;
  hi.x = (ha >> 16) | hb;
  hi.y = (hc >> 16) | hd;
  lo.x = pk2bf(v.x - __uint_as_float(ha), v.y - __uint_as_float(hb));
  lo.y = pk2bf(v.z - __uint_as_float(hc), v.w - __uint_as_float(hd));
}
// async global->LDS, 16B per lane; LDS dest = base + lane*16
__device__ __forceinline__ void gl_lds16(const void* g, void* l) {
  __builtin_amdgcn_global_load_lds((const __attribute__((address_space(1))) unsigned*)g,
                                   (__attribute__((address_space(3))) unsigned*)l, 16, 0, 0);
}

// ---------------- GroupNorm ----------------
__global__ void gn_stats_kernel(const float* __restrict__ x,
                                float* __restrict__ mu, float* __restrict__ rs) {
  const int grp = blockIdx.x;
  const float4* p = (const float4*)(x + (long)grp * GSIZE);
  float s = 0.f, q = 0.f;
  for (int i = threadIdx.x; i < GSIZE / 4; i += 256) {
    float4 v = p[i];
    s += (v.x + v.y) + (v.z + v.w);
    q += (v.x * v.x + v.y * v.y) + (v.z * v.z + v.w * v.w);
  }
  #pragma unroll
  for (int o = 32; o > 0; o >>= 1) { s += __shfl_xor(s, o, 64); q += __shfl_xor(q, o, 64); }
  __shared__ float ls[4], lq[4];
  if ((threadIdx.x & 63) == 0) { ls[threadIdx.x >> 6] = s; lq[threadIdx.x >> 6] = q; }
  __syncthreads();
  if (threadIdx.x == 0) {
    float S = (ls[0] + ls[1]) + (ls[2] + ls[3]);
    float Q = (lq[0] + lq[1]) + (lq[2] + lq[3]);
    float m = S * (1.f / GSIZE);
    float var = Q * (1.f / GSIZE) - m * m;
    mu[grp] = m; rs[grp] = rsqrtf(var + GN_EPS);
  }
}

__global__ void gn_norm_kernel(const float* __restrict__ x,
                               const float* __restrict__ mu, const float* __restrict__ rs,
                               const float* __restrict__ gw, const float* __restrict__ gb,
                               float* __restrict__ h) {
  long i = ((long)blockIdx.x * 256 + threadIdx.x) * 4;
  int c   = (int)((i >> 12) & 511);
  int grp = (int)(i >> 16);
  float m = mu[grp], r = rs[grp];
  float w = gw[c] * r;
  float bia = gb[c] - m * w;
  float4 v = *(const float4*)(x + i);
  v.x = v.x * w + bia; v.y = v.y * w + bia; v.z = v.z * w + bia; v.w = v.w * w + bia;
  *(float4*)(h + i) = v;
}

// ---------------- Projection GEMM, split-bf16 3-pass MFMA ----------------
// out[m, n] = sum_k A[m*512+k] * W[n*512+k] + bias[n] (+res) ; M=16384, N=512, K=512
// OMODE 0: f32 out; OMODE 1: bf16(ushort) out.
template<int OMODE, bool HASRES>
__launch_bounds__(256)
__global__ void proj_mfma(const float* __restrict__ A, const float* __restrict__ W,
                          const float* __restrict__ bias, const float* __restrict__ res,
                          void* __restrict__ outv) {
  __shared__ __align__(16) short Ah[8192], Al[8192], Bh[8192], Bl[8192];
  const int m0 = blockIdx.x * 128;
  const int n0 = blockIdx.y * 128;
  const int t = threadIdx.x, lane = t & 63, w = t >> 6, wm = w & 1, wn = w >> 1;
  const int srow = t >> 2, skg = t & 3;

  f32x4 acc[4][4];
  #pragma unroll
  for (int i = 0; i < 4; i++)
    #pragma unroll
    for (int j = 0; j < 4; j++) acc[i][j] = (f32x4){0.f, 0.f, 0.f, 0.f};

  float4 av[8], bv[8];
  #pragma unroll
  for (int it = 0; it < 8; it++) {
    int row = srow + 64 * (it & 1), kg = skg + 4 * (it >> 1);
    av[it] = *(const float4*)(A + (long)(m0 + row) * 512 + kg * 4);
    bv[it] = *(const float4*)(W + (long)(n0 + row) * 512 + kg * 4);
  }

  for (int k0 = 0; k0 < 512; k0 += 64) {
    __syncthreads();
    #pragma unroll
    for (int it = 0; it < 8; it++) {
      int row = srow + 64 * (it & 1), kg = skg + 4 * (it >> 1);
      int slot = ((((row >> 4) * 2 + (kg >> 3)) * 64 + (row & 15) + ((kg >> 1) & 3) * 16) << 3)
               + (kg & 1) * 4;
      uint2 h, l;
      split4(av[it], h, l);
      *(uint2*)&Ah[slot] = h; *(uint2*)&Al[slot] = l;
      split4(bv[it], h, l);
      *(uint2*)&Bh[slot] = h; *(uint2*)&Bl[slot] = l;
    }
    if (k0 + 64 < 512) {
      #pragma unroll
      for (int it = 0; it < 8; it++) {
        int row = srow + 64 * (it & 1), kg = skg + 4 * (it >> 1);
        av[it] = *(const float4*)(A + (long)(m0 + row) * 512 + k0 + 64 + kg * 4);
        bv[it] = *(const float4*)(W + (long)(n0 + row) * 512 + k0 + 64 + kg * 4);
      }
    }
    __syncthreads();
    #pragma unroll
    for (int kk = 0; kk < 2; kk++) {
      bf16x8 ah[4], al[4], bh[4], bl[4];
      #pragma unroll
      for (int i = 0; i < 4; i++) {
        int off = (((wm * 4 + i) * 2 + kk) * 64 + lane) << 3;
        ah[i] = *(const bf16x8*)&Ah[off];
        al[i] = *(const bf16x8*)&Al[off];
      }
      #pragma unroll
      for (int j = 0; j < 4; j++) {
        int off = (((wn * 4 + j) * 2 + kk) * 64 + lane) << 3;
        bh[j] = *(const bf16x8*)&Bh[off];
        bl[j] = *(const bf16x8*)&Bl[off];
      }
      #pragma unroll
      for (int i = 0; i < 4; i++)
        #pragma unroll
        for (int j = 0; j < 4; j++)
          acc[i][j] = __builtin_amdgcn_mfma_f32_16x16x32_bf16(ah[i], bh[j], acc[i][j], 0, 0, 0);
      #pragma unroll
      for (int i = 0; i < 4; i++)
        #pragma unroll
        for (int j = 0; j < 4; j++)
          acc[i][j] = __builtin_amdgcn_mfma_f32_16x16x32_bf16(ah[i], bl[j], acc[i][j], 0, 0, 0);
      #pragma unroll
      for (int i = 0; i < 4; i++)
        #pragma unroll
        for (int j = 0; j < 4; j++)
          acc[i][j] = __builtin_amdgcn_mfma_f32_16x16x32_bf16(al[i], bh[j], acc[i][j], 0, 0, 0);
    }
  }

  const int lm = lane & 15, quad = lane >> 4;
  #pragma unroll
  for (int i = 0; i < 4; i++)
    #pragma unroll
    for (int j = 0; j < 4; j++) {
      int nn = m0 + wm * 64 + i * 16 + quad * 4;
      int cc = n0 + wn * 64 + j * 16 + lm;
      float bb = bias[cc];
      #pragma unroll
      for (int r = 0; r < 4; r++) {
        long idx = (long)(nn + r) * 512 + cc;
        float val = acc[i][j][r] + bb;
        if (HASRES) val += res[idx];
        if (OMODE == 0) ((float*)outv)[idx] = val;
        else {
          union { float f; unsigned u; } z{val};
          ((unsigned short*)outv)[idx] = (unsigned short)((z.u + 0x8000u) >> 16);
        }
      }
    }
}

// ---------------- Transpose+split: [512][4096] f32 -> [4096][512] bf16 hi/lo ----------------
__global__ void transpose_split(const float* __restrict__ qb, const float* __restrict__ kb,
                                unsigned short* __restrict__ tr) {
  __shared__ float ld[64 * 65];
  const float* in = blockIdx.z ? kb : qb;
  unsigned short* oh = tr + (blockIdx.z ? 4194304 : 0);
  unsigned short* ol = oh + 2097152;
  const int n0 = blockIdx.x * 64, c0 = blockIdx.y * 64;
  const int t = threadIdx.x, m = t & 15, a = t >> 4;
  #pragma unroll
  for (int it = 0; it < 4; it++) {
    int c = a + 16 * it;
    float4 v = *(const float4*)(in + (long)(c0 + c) * 4096 + n0 + 4 * m);
    ld[c * 65 + 4 * m + 0] = v.x;
    ld[c * 65 + 4 * m + 1] = v.y;
    ld[c * 65 + 4 * m + 2] = v.z;
    ld[c * 65 + 4 * m + 3] = v.w;
  }
  __syncthreads();
  #pragma unroll
  for (int it = 0; it < 4; it++) {
    int n = a + 16 * it;
    float x0 = ld[(4 * m + 0) * 65 + n];
    float x1 = ld[(4 * m + 1) * 65 + n];
    float x2 = ld[(4 * m + 2) * 65 + n];
    float x3 = ld[(4 * m + 3) * 65 + n];
    union { float f; unsigned u; } u0{x0}, u1{x1}, u2{x2}, u3{x3};
    unsigned h0 = (u0.u + 0x8000u) & 0xFFFF0000u;
    unsigned h1 = (u1.u + 0x8000u) & 0xFFFF0000u;
    unsigned h2 = (u2.u + 0x8000u) & 0xFFFF0000u;
    unsigned h3 = (u3.u + 0x8000u) & 0xFFFF0000u;
    uint2 hp = { (h0 >> 16) | h1, (h2 >> 16) | h3 };
    uint2 lp = { pk2bf(x0 - __uint_as_float(h0), x1 - __uint_as_float(h1)),
                 pk2bf(x2 - __uint_as_float(h2), x3 - __uint_as_float(h3)) };
    long o = (long)(n0 + n) * 512 + c0 + 4 * m;
    *(uint2*)(oh + o) = hp;
    *(uint2*)(ol + o) = lp;
  }
}

// ---------------- QK^T, pre-split bf16 planes, DMA staging, 3-pass ----------------
// attn[n, m] = sum_c qT[n][c] * kT[m][c]; tiles 128x128, K=512, grid (32,32)
__launch_bounds__(256)
__global__ void qk_mfma(const unsigned short* __restrict__ tr, float* __restrict__ attn) {
  __shared__ __align__(16) short Ah[8192], Al[8192], Bh[8192], Bl[8192];
  const unsigned short* qh = tr;
  const unsigned short* ql = tr + 2097152;
  const unsigned short* kh = tr + 4194304;
  const unsigned short* kl = tr + 6291456;
  const int n0 = blockIdx.x * 128;
  const int m0 = blockIdx.y * 128;
  const int t = threadIdx.x, lane = t & 63, w = t >> 6, wm = w & 1, wn = w >> 1;

  f32x4 acc[4][4];
  #pragma unroll
  for (int i = 0; i < 4; i++)
    #pragma unroll
    for (int j = 0; j < 4; j++) acc[i][j] = (f32x4){0.f, 0.f, 0.f, 0.f};

  for (int k0 = 0; k0 < 512; k0 += 64) {
    __syncthreads();
    #pragma unroll
    for (int fbi = 0; fbi < 4; fbi++) {
      int fb = w * 4 + fbi;                      // 16 fb blocks per plane
      int row = (fb >> 1) * 16 + (lane & 15);
      int g   = (fb & 1) * 4 + (lane >> 4);
      long ao = (long)(n0 + row) * 512 + k0 + g * 8;
      long bo = (long)(m0 + row) * 512 + k0 + g * 8;
      gl_lds16(qh + ao, &Ah[(fb * 64) << 3]);
      gl_lds16(ql + ao, &Al[(fb * 64) << 3]);
      gl_lds16(kh + bo, &Bh[(fb * 64) << 3]);
      gl_lds16(kl + bo, &Bl[(fb * 64) << 3]);
    }
    __syncthreads();
    #pragma unroll
    for (int kk = 0; kk < 2; kk++) {
      bf16x8 ah[4], al[4], bh[4], bl[4];
      #pragma unroll
      for (int i = 0; i < 4; i++) {
        int off = (((wm * 4 + i) * 2 + kk) * 64 + lane) << 3;
        ah[i] = *(const bf16x8*)&Ah[off];
        al[i] = *(const bf16x8*)&Al[off];
      }
      #pragma unroll
      for (int j = 0; j < 4; j++) {
        int off = (((wn * 4 + j) * 2 + kk) * 64 + lane) << 3;
        bh[j] = *(const bf16x8*)&Bh[off];
        bl[j] = *(const bf16x8*)&Bl[off];
      }
      #pragma unroll
      for (int i = 0; i < 4; i++)
        #pragma unroll
        for (int j = 0; j < 4; j++)
          acc[i][j] = __builtin_amdgcn_mfma_f32_16x16x32_bf16(ah[i], bh[j], acc[i][j], 0, 0, 0);
      #pragma unroll
      for (int i = 0; i < 4; i++)
        #pragma unroll
        for (int j = 0; j < 4; j++)
          acc[i][j] = __builtin_amdgcn_mfma_f32_16x16x32_bf16(ah[i], bl[j], acc[i][j], 0, 0, 0);
      #pragma unroll
      for (int i = 0; i < 4; i++)
        #pragma unroll
        for (int j = 0; j < 4; j++)
          acc[i][j] = __builtin_amdgcn_mfma_f32_16x16x32_bf16(al[i], bh[j], acc[i][j], 0, 0, 0);
    }
  }

  const int lm = lane & 15, quad = lane >> 4;
  #pragma unroll
  for (int i = 0; i < 4; i++)
    #pragma unroll
    for (int j = 0; j < 4; j++) {
      int nn = n0 + wm * 64 + i * 16 + quad * 4;
      int mm = m0 + wn * 64 + j * 16 + lm;
      #pragma unroll
      for (int r = 0; r < 4; r++)
        attn[(long)(nn + r) * 4096 + mm] = acc[i][j][r];
    }
}

// ---------------- Row softmax ----------------
__global__ void softmax_kernel(float* __restrict__ attn) {
  float* p = attn + (long)blockIdx.x * HWDIM;
  const int t = threadIdx.x;
  float4 v[4];
  float mx = -1e30f;
  #pragma unroll
  for (int u = 0; u < 4; u++) {
    v[u] = ((const float4*)p)[t + u * 256];
    mx = fmaxf(mx, fmaxf(fmaxf(v[u].x, v[u].y), fmaxf(v[u].z, v[u].w)));
  }
  #pragma unroll
  for (int o = 32; o > 0; o >>= 1) mx = fmaxf(mx, __shfl_xor(mx, o, 64));
  __shared__ float rmax[4], rsum[4];
  if ((t & 63) == 0) rmax[t >> 6] = mx;
  __syncthreads();
  mx = fmaxf(fmaxf(rmax[0], rmax[1]), fmaxf(rmax[2], rmax[3]));
  float s = 0.f;
  #pragma unroll
  for (int u = 0; u < 4; u++) {
    v[u].x = __expf(v[u].x - mx); v[u].y = __expf(v[u].y - mx);
    v[u].z = __expf(v[u].z - mx); v[u].w = __expf(v[u].w - mx);
    s += (v[u].x + v[u].y) + (v[u].z + v[u].w);
  }
  #pragma unroll
  for (int o = 32; o > 0; o >>= 1) s += __shfl_xor(s, o, 64);
  if ((t & 63) == 0) rsum[t >> 6] = s;
  __syncthreads();
  s = (rsum[0] + rsum[1]) + (rsum[2] + rsum[3]);
  float inv = 1.f / s;
  #pragma unroll
  for (int u = 0; u < 4; u++) {
    v[u].x *= inv; v[u].y *= inv; v[u].z *= inv; v[u].w *= inv;
    ((float4*)p)[t + u * 256] = v[u];
  }
}

// ---------------- PV: f32 P (convert) x bf16 V plane (DMA), single-pass ----------------
__launch_bounds__(256)
__global__ void pv_mfma(const float* __restrict__ P, const unsigned short* __restrict__ Vbf,
                        float* __restrict__ out0, float* __restrict__ out1) {
  __shared__ __align__(16) short As[8192];
  __shared__ __align__(16) short Bs[8192];
  const int n0 = blockIdx.x * 128;
  const int c0 = blockIdx.y * 128;
  const long kbase = (long)blockIdx.z * 2048;
  float* __restrict__ Pout = blockIdx.z ? out1 : out0;
  const int t = threadIdx.x, lane = t & 63, w = t >> 6, wm = w & 1, wn = w >> 1;
  const int srow = t >> 2, skg = t & 3;

  f32x4 acc[4][4];
  #pragma unroll
  for (int i = 0; i < 4; i++)
    #pragma unroll
    for (int j = 0; j < 4; j++) acc[i][j] = (f32x4){0.f, 0.f, 0.f, 0.f};

  float4 av[8];
  #pragma unroll
  for (int it = 0; it < 8; it++) {
    int row = srow + 64 * (it & 1), kg = skg + 4 * (it >> 1);
    av[it] = *(const float4*)(P + (long)(n0 + row) * 4096 + kbase + kg * 4);
  }

  for (int k0 = 0; k0 < 2048; k0 += 64) {
    __syncthreads();
    #pragma unroll
    for (int fbi = 0; fbi < 4; fbi++) {
      int fb = w * 4 + fbi;
      int row = (fb >> 1) * 16 + (lane & 15);
      int g   = (fb & 1) * 4 + (lane >> 4);
      gl_lds16(Vbf + (long)(c0 + row) * 4096 + kbase + k0 + g * 8, &Bs[(fb * 64) << 3]);
    }
    #pragma unroll
    for (int it = 0; it < 8; it++) {
      int row = srow + 64 * (it & 1), kg = skg + 4 * (it >> 1);
      int slot = ((((row >> 4) * 2 + (kg >> 3)) * 64 + (row & 15) + ((kg >> 1) & 3) * 16) << 3)
               + (kg & 1) * 4;
      *(uint2*)&As[slot] = (uint2){ pk2bf(av[it].x, av[it].y), pk2bf(av[it].z, av[it].w) };
    }
    if (k0 + 64 < 2048) {
      #pragma unroll
      for (int it = 0; it < 8; it++) {
        int row = srow + 64 * (it & 1), kg = skg + 4 * (it >> 1);
        av[it] = *(const float4*)(P + (long)(n0 + row) * 4096 + kbase + k0 + 64 + kg * 4);
      }
    }
    __syncthreads();
    #pragma unroll
    for (int kk = 0; kk < 2; kk++) {
      bf16x8 a[4], b[4];
      #pragma unroll
      for (int i = 0; i < 4; i++)
        a[i] = *(const bf16x8*)&As[(((wm * 4 + i) * 2 + kk) * 64 + lane) << 3];
      #pragma unroll
      for (int j = 0; j < 4; j++)
        b[j] = *(const bf16x8*)&Bs[(((wn * 4 + j) * 2 + kk) * 64 + lane) << 3];
      #pragma unroll
      for (int i = 0; i < 4; i++)
        #pragma unroll
        for (int j = 0; j < 4; j++)
          acc[i][j] = __builtin_amdgcn_mfma_f32_16x16x32_bf16(a[i], b[j], acc[i][j], 0, 0, 0);
    }
  }

  const int lm = lane & 15, quad = lane >> 4;
  #pragma unroll
  for (int i = 0; i < 4; i++)
    #pragma unroll
    for (int j = 0; j < 4; j++) {
      int nn = n0 + wm * 64 + i * 16 + quad * 4;
      int cc = c0 + wn * 64 + j * 16 + lm;
      #pragma unroll
      for (int r = 0; r < 4; r++)
        Pout[(long)(nn + r) * 512 + cc] = acc[i][j][r];
    }
}

// ---------------- a += b ----------------
__global__ void add2_kernel(float* __restrict__ a, const float* __restrict__ b) {
  long i = ((long)blockIdx.x * 256 + threadIdx.x) * 4;
  float4 va = *(float4*)(a + i);
  float4 vb = *(const float4*)(b + i);
  va.x += vb.x; va.y += vb.y; va.z += vb.z; va.w += vb.w;
  *(float4*)(a + i) = va;
}

// ---------------- launch ----------------
extern "C" void kernel_launch(void* const* d_in, const int* in_sizes, int n_in,
                              void* d_out, int out_size, void* d_ws, size_t ws_size,
                              hipStream_t stream) {
  (void)in_sizes; (void)n_in; (void)out_size; (void)ws_size;
  const float* x  = (const float*)d_in[0];
  const float* gw = (const float*)d_in[1];
  const float* gb = (const float*)d_in[2];
  const float* wq = (const float*)d_in[3];
  const float* bq = (const float*)d_in[4];
  const float* wk = (const float*)d_in[5];
  const float* bk = (const float*)d_in[6];
  const float* wv = (const float*)d_in[7];
  const float* bv = (const float*)d_in[8];
  const float* wo = (const float*)d_in[9];
  const float* bo = (const float*)d_in[10];
  float* out = (float*)d_out;
  float* ws  = (float*)d_ws;

  // Workspace (160 MB + 1 KB):
  //   [attn 64MB f32][q 32MB f32][k 32MB f32][vbf 16MB bf16][tr 16MB bf16][mu/rs]
  // h (32MB) aliases attn start. PV partials reuse q_b (z=0) / k_b (z=1),
  // both dead after transpose(b). ot accumulates in q region for out-proj.
  float* attn = ws;
  float* h    = ws;
  float* q    = ws + 16777216;
  float* k    = q + 8388608;
  unsigned short* vbf = (unsigned short*)(k + 8388608);
  unsigned short* tr  = vbf + 8388608;
  float* mu   = (float*)(tr + 8388608);
  float* rs   = mu + 128;

  gn_stats_kernel<<<dim3(128), dim3(256), 0, stream>>>(x, mu, rs);
  gn_norm_kernel<<<dim3(8192), dim3(256), 0, stream>>>(x, mu, rs, gw, gb, h);

  dim3 gproj(128, 4);
  proj_mfma<0, false><<<gproj, 256, 0, stream>>>(h, wq, bq, nullptr, q);
  proj_mfma<0, false><<<gproj, 256, 0, stream>>>(h, wk, bk, nullptr, k);
  proj_mfma<1, false><<<gproj, 256, 0, stream>>>(h, wv, bv, nullptr, vbf);

  for (int b = 0; b < BATCH; b++) {
    float* qb = q + (long)b * CN;
    float* kb = k + (long)b * CN;
    transpose_split<<<dim3(64, 8, 2), 256, 0, stream>>>(qb, kb, tr);
    qk_mfma<<<dim3(32, 32), 256, 0, stream>>>(tr, attn);
    softmax_kernel<<<dim3(4096), dim3(256), 0, stream>>>(attn);
    pv_mfma<<<dim3(32, 4, 2), 256, 0, stream>>>(attn, vbf + (long)b * CN, qb, kb);
    add2_kernel<<<dim3(2048), 256, 0, stream>>>(qb, kb);
  }
  proj_mfma<0, true><<<gproj, 256, 0, stream>>>(q, wo, bo, x, out);
}

// Round 4
// 605.812 us; speedup vs baseline: 5.2410x; 1.6012x over previous
//
#include <hip/hip_runtime.h>
#include <hip/hip_fp16.h>
#include <math.h>

// Shapes (fixed): B=4, C=512, H=W=64 -> HW=4096
constexpr int BATCH = 4;
constexpr int HWDIM = 4096;
constexpr long CNT  = 2097152;               // 4096*512 elems per batch
constexpr int GSIZE = 65536;
constexpr float GN_EPS = 1e-5f;

typedef __attribute__((ext_vector_type(8))) _Float16 f16x8;
typedef __attribute__((ext_vector_type(4))) float f32x4;

__device__ __forceinline__ unsigned pkf16(float a, float b) {
  __half ha = __float2half(a), hb = __float2half(b);   // RTN
  return (unsigned)__half_as_ushort(ha) | ((unsigned)__half_as_ushort(hb) << 16);
}
__device__ __forceinline__ float2 up2(unsigned u) {
  __half2 h = *(__half2*)&u;
  return __half22float2(h);
}
// async global->LDS, 16B per lane; LDS dest = base + lane*16
__device__ __forceinline__ void gl_lds16(const void* g, void* l) {
  __builtin_amdgcn_global_load_lds((const __attribute__((address_space(1))) unsigned*)g,
                                   (__attribute__((address_space(3))) unsigned*)l, 16, 0, 0);
}

// ---------------- GroupNorm ----------------
__global__ void gn_stats_kernel(const float* __restrict__ x,
                                float* __restrict__ mu, float* __restrict__ rs) {
  const int grp = blockIdx.x;
  const float4* p = (const float4*)(x + (long)grp * GSIZE);
  float s = 0.f, q = 0.f;
  for (int i = threadIdx.x; i < GSIZE / 4; i += 256) {
    float4 v = p[i];
    s += (v.x + v.y) + (v.z + v.w);
    q += (v.x * v.x + v.y * v.y) + (v.z * v.z + v.w * v.w);
  }
  #pragma unroll
  for (int o = 32; o > 0; o >>= 1) { s += __shfl_xor(s, o, 64); q += __shfl_xor(q, o, 64); }
  __shared__ float ls[4], lq[4];
  if ((threadIdx.x & 63) == 0) { ls[threadIdx.x >> 6] = s; lq[threadIdx.x >> 6] = q; }
  __syncthreads();
  if (threadIdx.x == 0) {
    float S = (ls[0] + ls[1]) + (ls[2] + ls[3]);
    float Q = (lq[0] + lq[1]) + (lq[2] + lq[3]);
    float m = S * (1.f / GSIZE);
    float var = Q * (1.f / GSIZE) - m * m;
    mu[grp] = m; rs[grp] = rsqrtf(var + GN_EPS);
  }
}

// normalize + affine, fp16 output
__global__ void gn_norm_f16(const float* __restrict__ x,
                            const float* __restrict__ mu, const float* __restrict__ rs,
                            const float* __restrict__ gw, const float* __restrict__ gb,
                            unsigned short* __restrict__ h) {
  long i = ((long)blockIdx.x * 256 + threadIdx.x) * 4;
  int c   = (int)((i >> 12) & 511);
  int grp = (int)(i >> 16);
  float m = mu[grp], r = rs[grp];
  float w = gw[c] * r;
  float bia = gb[c] - m * w;
  float4 v = *(const float4*)(x + i);
  uint2 o = { pkf16(v.x * w + bia, v.y * w + bia), pkf16(v.z * w + bia, v.w * w + bia) };
  *(uint2*)(h + i) = o;
}

// ---------------- weights -> fp16 (once per launch) ----------------
__global__ void wcvt(const float* __restrict__ w0, const float* __restrict__ w1,
                     const float* __restrict__ w2, const float* __restrict__ w3,
                     unsigned short* __restrict__ o) {
  const float* src = blockIdx.y == 0 ? w0 : blockIdx.y == 1 ? w1 : blockIdx.y == 2 ? w2 : w3;
  long e = ((long)blockIdx.x * 256 + threadIdx.x) * 4;
  float4 v = *(const float4*)(src + e);
  *(uint2*)(o + (long)blockIdx.y * 262144 + e) = (uint2){ pkf16(v.x, v.y), pkf16(v.z, v.w) };
}

// ---------------- Projection GEMM, single-pass fp16, full-DMA staging ----------------
// out[m,n] = sum_k A[m*512+k]*W[n*512+k] + bias[n]; M=16384, N=512, K=512.
// OMODE 1: fp16 out, no res. OMODE 0: f32 out + res (final out-proj).
template<int OMODE>
__launch_bounds__(256)
__global__ void proj_f16(const unsigned short* __restrict__ A, const unsigned short* __restrict__ W,
                         const float* __restrict__ bias, const float* __restrict__ res,
                         void* __restrict__ outv) {
  __shared__ __align__(16) unsigned short As[8192], Bs[8192];
  const int m0 = blockIdx.x * 128, n0 = blockIdx.y * 128;
  const int t = threadIdx.x, lane = t & 63, w = t >> 6, wm = w & 1, wn = w >> 1;

  f32x4 acc[4][4];
  #pragma unroll
  for (int i = 0; i < 4; i++)
    #pragma unroll
    for (int j = 0; j < 4; j++) acc[i][j] = (f32x4){0.f, 0.f, 0.f, 0.f};

  for (int k0 = 0; k0 < 512; k0 += 64) {
    __syncthreads();
    #pragma unroll
    for (int fbi = 0; fbi < 4; fbi++) {
      int fb = w * 4 + fbi;
      int row = (fb >> 1) * 16 + (lane & 15);
      int g   = (fb & 1) * 4 + (lane >> 4);
      gl_lds16(A + (long)(m0 + row) * 512 + k0 + g * 8, &As[(fb * 64) << 3]);
      gl_lds16(W + (long)(n0 + row) * 512 + k0 + g * 8, &Bs[(fb * 64) << 3]);
    }
    __syncthreads();
    #pragma unroll
    for (int kk = 0; kk < 2; kk++) {
      f16x8 a[4], b[4];
      #pragma unroll
      for (int i = 0; i < 4; i++)
        a[i] = *(const f16x8*)&As[(((wm * 4 + i) * 2 + kk) * 64 + lane) << 3];
      #pragma unroll
      for (int j = 0; j < 4; j++)
        b[j] = *(const f16x8*)&Bs[(((wn * 4 + j) * 2 + kk) * 64 + lane) << 3];
      #pragma unroll
      for (int i = 0; i < 4; i++)
        #pragma unroll
        for (int j = 0; j < 4; j++)
          acc[i][j] = __builtin_amdgcn_mfma_f32_16x16x32_f16(a[i], b[j], acc[i][j], 0, 0, 0);
    }
  }

  const int lm = lane & 15, quad = lane >> 4;
  #pragma unroll
  for (int i = 0; i < 4; i++)
    #pragma unroll
    for (int j = 0; j < 4; j++) {
      int nn = m0 + wm * 64 + i * 16 + quad * 4;
      int cc = n0 + wn * 64 + j * 16 + lm;
      float bb = bias[cc];
      #pragma unroll
      for (int r = 0; r < 4; r++) {
        long idx = (long)(nn + r) * 512 + cc;
        float val = acc[i][j][r] + bb;
        if (OMODE == 0) ((float*)outv)[idx] = val + res[idx];
        else ((unsigned short*)outv)[idx] = __half_as_ushort(__float2half(val));
      }
    }
}

// ---------------- Transpose fp16: (512,4096)-view -> [4096][512] ----------------
__global__ void transpose_f16(const unsigned short* __restrict__ qb,
                              const unsigned short* __restrict__ kb,
                              unsigned short* __restrict__ tr) {
  __shared__ __align__(16) unsigned short ld[64 * 72];   // [n(64)][c(64)+pad8]
  const unsigned short* in = blockIdx.z ? kb : qb;
  unsigned short* o = tr + (blockIdx.z ? 2097152 : 0);
  const int n0 = blockIdx.x * 64, c0 = blockIdx.y * 64;
  const int t = threadIdx.x;
  unsigned* ld32 = (unsigned*)ld;
  {
    const int p = t >> 3, cg = t & 7;        // row-pair p (c dim), col-group cg (n dim)
    uint4 r0 = *(const uint4*)(in + (long)(c0 + 2 * p) * 4096 + n0 + 8 * cg);
    uint4 r1 = *(const uint4*)(in + (long)(c0 + 2 * p + 1) * 4096 + n0 + 8 * cg);
    unsigned aw[4] = { r0.x, r0.y, r0.z, r0.w };
    unsigned bw[4] = { r1.x, r1.y, r1.z, r1.w };
    #pragma unroll
    for (int i = 0; i < 4; i++) {
      ld32[(8 * cg + 2 * i) * 36 + p]     = (aw[i] & 0xFFFFu) | (bw[i] << 16);
      ld32[(8 * cg + 2 * i + 1) * 36 + p] = (aw[i] >> 16) | (bw[i] & 0xFFFF0000u);
    }
  }
  __syncthreads();
  {
    const int n = t >> 2, cg2 = t & 3;
    uint4 o0 = *(const uint4*)(ld + n * 72 + 16 * cg2);
    uint4 o1 = *(const uint4*)(ld + n * 72 + 16 * cg2 + 8);
    *(uint4*)(o + (long)(n0 + n) * 512 + c0 + 16 * cg2)     = o0;
    *(uint4*)(o + (long)(n0 + n) * 512 + c0 + 16 * cg2 + 8) = o1;
  }
}

// ---------------- QK^T single-pass fp16, full DMA ----------------
// attn[n,m] = sum_c qT[n][c]*kT[m][c]; 128x128 tiles, K=512, grid (32,32)
__launch_bounds__(256)
__global__ void qk_f16(const unsigned short* __restrict__ tr, float* __restrict__ attn) {
  __shared__ __align__(16) unsigned short As[8192], Bs[8192];
  const unsigned short* qT = tr;
  const unsigned short* kT = tr + 2097152;
  const int n0 = blockIdx.x * 128, m0 = blockIdx.y * 128;
  const int t = threadIdx.x, lane = t & 63, w = t >> 6, wm = w & 1, wn = w >> 1;

  f32x4 acc[4][4];
  #pragma unroll
  for (int i = 0; i < 4; i++)
    #pragma unroll
    for (int j = 0; j < 4; j++) acc[i][j] = (f32x4){0.f, 0.f, 0.f, 0.f};

  for (int k0 = 0; k0 < 512; k0 += 64) {
    __syncthreads();
    #pragma unroll
    for (int fbi = 0; fbi < 4; fbi++) {
      int fb = w * 4 + fbi;
      int row = (fb >> 1) * 16 + (lane & 15);
      int g   = (fb & 1) * 4 + (lane >> 4);
      gl_lds16(qT + (long)(n0 + row) * 512 + k0 + g * 8, &As[(fb * 64) << 3]);
      gl_lds16(kT + (long)(m0 + row) * 512 + k0 + g * 8, &Bs[(fb * 64) << 3]);
    }
    __syncthreads();
    #pragma unroll
    for (int kk = 0; kk < 2; kk++) {
      f16x8 a[4], b[4];
      #pragma unroll
      for (int i = 0; i < 4; i++)
        a[i] = *(const f16x8*)&As[(((wm * 4 + i) * 2 + kk) * 64 + lane) << 3];
      #pragma unroll
      for (int j = 0; j < 4; j++)
        b[j] = *(const f16x8*)&Bs[(((wn * 4 + j) * 2 + kk) * 64 + lane) << 3];
      #pragma unroll
      for (int i = 0; i < 4; i++)
        #pragma unroll
        for (int j = 0; j < 4; j++)
          acc[i][j] = __builtin_amdgcn_mfma_f32_16x16x32_f16(a[i], b[j], acc[i][j], 0, 0, 0);
    }
  }

  const int lm = lane & 15, quad = lane >> 4;
  #pragma unroll
  for (int i = 0; i < 4; i++)
    #pragma unroll
    for (int j = 0; j < 4; j++) {
      int nn = n0 + wm * 64 + i * 16 + quad * 4;
      int mm = m0 + wn * 64 + j * 16 + lm;
      #pragma unroll
      for (int r = 0; r < 4; r++)
        attn[(long)(nn + r) * 4096 + mm] = acc[i][j][r];
    }
}

// ---------------- Row softmax: f32 in, fp16 out IN-PLACE (row-local) ----------------
// P row n occupies the first 8192 bytes of f32 row n (stride 8192 shorts).
__global__ void softmax_f16(float* __restrict__ attn) {
  float* p = attn + (long)blockIdx.x * HWDIM;
  unsigned short* po = (unsigned short*)attn + (long)blockIdx.x * 8192;
  const int t = threadIdx.x;
  float4 v[4];
  float mx = -1e30f;
  #pragma unroll
  for (int u = 0; u < 4; u++) {
    v[u] = ((const float4*)p)[t + u * 256];
    mx = fmaxf(mx, fmaxf(fmaxf(v[u].x, v[u].y), fmaxf(v[u].z, v[u].w)));
  }
  #pragma unroll
  for (int o = 32; o > 0; o >>= 1) mx = fmaxf(mx, __shfl_xor(mx, o, 64));
  __shared__ float rmax[4], rsum[4];
  if ((t & 63) == 0) rmax[t >> 6] = mx;
  __syncthreads();
  mx = fmaxf(fmaxf(rmax[0], rmax[1]), fmaxf(rmax[2], rmax[3]));
  float s = 0.f;
  #pragma unroll
  for (int u = 0; u < 4; u++) {
    v[u].x = __expf(v[u].x - mx); v[u].y = __expf(v[u].y - mx);
    v[u].z = __expf(v[u].z - mx); v[u].w = __expf(v[u].w - mx);
    s += (v[u].x + v[u].y) + (v[u].z + v[u].w);
  }
  #pragma unroll
  for (int o = 32; o > 0; o >>= 1) s += __shfl_xor(s, o, 64);
  if ((t & 63) == 0) rsum[t >> 6] = s;
  __syncthreads();   // also guarantees all f32 reads complete before fp16 writes
  s = (rsum[0] + rsum[1]) + (rsum[2] + rsum[3]);
  float inv = 1.f / s;
  #pragma unroll
  for (int u = 0; u < 4; u++) {
    long e = 4 * (t + 256 * u);
    *(uint2*)(po + e) = (uint2){ pkf16(v[u].x * inv, v[u].y * inv),
                                 pkf16(v[u].z * inv, v[u].w * inv) };
  }
}

// ---------------- PV: fp16 P (stride 8192) x fp16 V, full DMA, split-K 4 ----------------
// partial[n,c] = sum_{m in z-quarter} P[n,m]*V[c,m]; out fp16 partials (4 planes)
__launch_bounds__(256)
__global__ void pv_f16(const unsigned short* __restrict__ P, const unsigned short* __restrict__ V,
                       unsigned short* __restrict__ pvp) {
  __shared__ __align__(16) unsigned short As[8192], Bs[8192];
  const int n0 = blockIdx.x * 128, c0 = blockIdx.y * 128;
  const long kbase = (long)blockIdx.z * 1024;
  unsigned short* __restrict__ Pout = pvp + (long)blockIdx.z * 2097152;
  const int t = threadIdx.x, lane = t & 63, w = t >> 6, wm = w & 1, wn = w >> 1;

  f32x4 acc[4][4];
  #pragma unroll
  for (int i = 0; i < 4; i++)
    #pragma unroll
    for (int j = 0; j < 4; j++) acc[i][j] = (f32x4){0.f, 0.f, 0.f, 0.f};

  for (int k0 = 0; k0 < 1024; k0 += 64) {
    __syncthreads();
    #pragma unroll
    for (int fbi = 0; fbi < 4; fbi++) {
      int fb = w * 4 + fbi;
      int row = (fb >> 1) * 16 + (lane & 15);
      int g   = (fb & 1) * 4 + (lane >> 4);
      gl_lds16(P + (long)(n0 + row) * 8192 + kbase + k0 + g * 8, &As[(fb * 64) << 3]);
      gl_lds16(V + (long)(c0 + row) * 4096 + kbase + k0 + g * 8, &Bs[(fb * 64) << 3]);
    }
    __syncthreads();
    #pragma unroll
    for (int kk = 0; kk < 2; kk++) {
      f16x8 a[4], b[4];
      #pragma unroll
      for (int i = 0; i < 4; i++)
        a[i] = *(const f16x8*)&As[(((wm * 4 + i) * 2 + kk) * 64 + lane) << 3];
      #pragma unroll
      for (int j = 0; j < 4; j++)
        b[j] = *(const f16x8*)&Bs[(((wn * 4 + j) * 2 + kk) * 64 + lane) << 3];
      #pragma unroll
      for (int i = 0; i < 4; i++)
        #pragma unroll
        for (int j = 0; j < 4; j++)
          acc[i][j] = __builtin_amdgcn_mfma_f32_16x16x32_f16(a[i], b[j], acc[i][j], 0, 0, 0);
    }
  }

  const int lm = lane & 15, quad = lane >> 4;
  #pragma unroll
  for (int i = 0; i < 4; i++)
    #pragma unroll
    for (int j = 0; j < 4; j++) {
      int nn = n0 + wm * 64 + i * 16 + quad * 4;
      int cc = c0 + wn * 64 + j * 16 + lm;
      #pragma unroll
      for (int r = 0; r < 4; r++)
        Pout[(long)(nn + r) * 512 + cc] = __half_as_ushort(__float2half(acc[i][j][r]));
    }
}

// ---------------- sum 4 fp16 partials -> fp16 ot ----------------
__global__ void add4_f16(const unsigned short* __restrict__ p, unsigned short* __restrict__ o) {
  long e = ((long)blockIdx.x * 256 + threadIdx.x) * 4;
  float sx = 0.f, sy = 0.f, sz = 0.f, sw = 0.f;
  #pragma unroll
  for (int z = 0; z < 4; z++) {
    uint2 u = *(const uint2*)(p + (long)z * 2097152 + e);
    float2 f0 = up2(u.x), f1 = up2(u.y);
    sx += f0.x; sy += f0.y; sz += f1.x; sw += f1.y;
  }
  *(uint2*)(o + e) = (uint2){ pkf16(sx, sy), pkf16(sz, sw) };
}

// ---------------- launch ----------------
extern "C" void kernel_launch(void* const* d_in, const int* in_sizes, int n_in,
                              void* d_out, int out_size, void* d_ws, size_t ws_size,
                              hipStream_t stream) {
  (void)in_sizes; (void)n_in; (void)out_size; (void)ws_size;
  const float* x  = (const float*)d_in[0];
  const float* gw = (const float*)d_in[1];
  const float* gb = (const float*)d_in[2];
  const float* wq = (const float*)d_in[3];
  const float* bq = (const float*)d_in[4];
  const float* wk = (const float*)d_in[5];
  const float* bk = (const float*)d_in[6];
  const float* wv = (const float*)d_in[7];
  const float* bv = (const float*)d_in[8];
  const float* wo = (const float*)d_in[9];
  const float* bo = (const float*)d_in[10];
  float* out = (float*)d_out;
  float* ws  = (float*)d_ws;

  // Workspace (154 MB + 1 KB < previous 160 MB):
  //  [attn f32 64MB | h fp16 16MB aliases start][q f16 16][k f16 16][v f16 16]
  //  [tr f16 8][pv partials f16 16][ot f16 16][w f16 2][mu/rs]
  float* attn = ws;
  unsigned short* h   = (unsigned short*)ws;
  unsigned short* qf  = (unsigned short*)(ws + 16777216);
  unsigned short* kf  = qf + 8388608;
  unsigned short* vf  = kf + 8388608;
  unsigned short* tr  = vf + 8388608;
  unsigned short* pvp = tr + 4194304;
  unsigned short* ot  = pvp + 8388608;
  unsigned short* wf  = ot + 8388608;
  float* mu = (float*)(wf + 1048576);
  float* rs = mu + 128;

  gn_stats_kernel<<<dim3(128), dim3(256), 0, stream>>>(x, mu, rs);
  gn_norm_f16<<<dim3(8192), dim3(256), 0, stream>>>(x, mu, rs, gw, gb, h);
  wcvt<<<dim3(256, 4), dim3(256), 0, stream>>>(wq, wk, wv, wo, wf);

  dim3 gproj(128, 4);
  proj_f16<1><<<gproj, 256, 0, stream>>>(h, wf,          bq, nullptr, qf);
  proj_f16<1><<<gproj, 256, 0, stream>>>(h, wf + 262144, bk, nullptr, kf);
  proj_f16<1><<<gproj, 256, 0, stream>>>(h, wf + 524288, bv, nullptr, vf);

  for (int b = 0; b < BATCH; b++) {
    transpose_f16<<<dim3(64, 8, 2), 256, 0, stream>>>(qf + (long)b * CNT, kf + (long)b * CNT, tr);
    qk_f16<<<dim3(32, 32), 256, 0, stream>>>(tr, attn);
    softmax_f16<<<dim3(4096), 256, 0, stream>>>(attn);
    pv_f16<<<dim3(32, 4, 4), 256, 0, stream>>>((const unsigned short*)attn, vf + (long)b * CNT, pvp);
    add4_f16<<<dim3(2048), 256, 0, stream>>>(pvp, ot + (long)b * CNT);
  }
  proj_f16<0><<<gproj, 256, 0, stream>>>(ot, wf + 786432, bo, x, (void*)out);
}

// Round 5
// 591.826 us; speedup vs baseline: 5.3649x; 1.0236x over previous
//
#include <hip/hip_runtime.h>
#include <hip/hip_fp16.h>
#include <math.h>

// Shapes (fixed): B=4, C=512, H=W=64 -> HW=4096
constexpr int BATCH = 4;
constexpr int HWDIM = 4096;
constexpr long CNT  = 2097152;               // 4096*512 elems per batch
constexpr int GSIZE = 65536;
constexpr float GN_EPS = 1e-5f;

typedef __attribute__((ext_vector_type(8))) _Float16 f16x8;
typedef __attribute__((ext_vector_type(4))) float f32x4;

__device__ __forceinline__ unsigned pkf16(float a, float b) {
  __half ha = __float2half(a), hb = __float2half(b);   // RTN
  return (unsigned)__half_as_ushort(ha) | ((unsigned)__half_as_ushort(hb) << 16);
}
__device__ __forceinline__ float2 up2(unsigned u) {
  __half2 h = *(__half2*)&u;
  return __half22float2(h);
}
// async global->LDS, 16B per lane; LDS dest = base + lane*16
__device__ __forceinline__ void gl_lds16(const void* g, void* l) {
  __builtin_amdgcn_global_load_lds((const __attribute__((address_space(1))) unsigned*)g,
                                   (__attribute__((address_space(3))) unsigned*)l, 16, 0, 0);
}

// ---------------- GroupNorm ----------------
__global__ void gn_stats_kernel(const float* __restrict__ x,
                                float* __restrict__ mu, float* __restrict__ rs) {
  const int grp = blockIdx.x;
  const float4* p = (const float4*)(x + (long)grp * GSIZE);
  float s = 0.f, q = 0.f;
  for (int i = threadIdx.x; i < GSIZE / 4; i += 256) {
    float4 v = p[i];
    s += (v.x + v.y) + (v.z + v.w);
    q += (v.x * v.x + v.y * v.y) + (v.z * v.z + v.w * v.w);
  }
  #pragma unroll
  for (int o = 32; o > 0; o >>= 1) { s += __shfl_xor(s, o, 64); q += __shfl_xor(q, o, 64); }
  __shared__ float ls[4], lq[4];
  if ((threadIdx.x & 63) == 0) { ls[threadIdx.x >> 6] = s; lq[threadIdx.x >> 6] = q; }
  __syncthreads();
  if (threadIdx.x == 0) {
    float S = (ls[0] + ls[1]) + (ls[2] + ls[3]);
    float Q = (lq[0] + lq[1]) + (lq[2] + lq[3]);
    float m = S * (1.f / GSIZE);
    float var = Q * (1.f / GSIZE) - m * m;
    mu[grp] = m; rs[grp] = rsqrtf(var + GN_EPS);
  }
}

__global__ void gn_norm_f16(const float* __restrict__ x,
                            const float* __restrict__ mu, const float* __restrict__ rs,
                            const float* __restrict__ gw, const float* __restrict__ gb,
                            unsigned short* __restrict__ h) {
  long i = ((long)blockIdx.x * 256 + threadIdx.x) * 4;
  int c   = (int)((i >> 12) & 511);
  int grp = (int)(i >> 16);
  float m = mu[grp], r = rs[grp];
  float w = gw[c] * r;
  float bia = gb[c] - m * w;
  float4 v = *(const float4*)(x + i);
  *(uint2*)(h + i) = (uint2){ pkf16(v.x * w + bia, v.y * w + bia),
                              pkf16(v.z * w + bia, v.w * w + bia) };
}

// ---------------- weights -> fp16 ----------------
__global__ void wcvt(const float* __restrict__ w0, const float* __restrict__ w1,
                     const float* __restrict__ w2, const float* __restrict__ w3,
                     unsigned short* __restrict__ o) {
  const float* src = blockIdx.y == 0 ? w0 : blockIdx.y == 1 ? w1 : blockIdx.y == 2 ? w2 : w3;
  long e = ((long)blockIdx.x * 256 + threadIdx.x) * 4;
  float4 v = *(const float4*)(src + e);
  *(uint2*)(o + (long)blockIdx.y * 262144 + e) = (uint2){ pkf16(v.x, v.y), pkf16(v.z, v.w) };
}

// ---------------- Projection GEMM, fp16 MFMA, full-DMA staging ----------------
// out[m,n] = sum_k A[m*512+k]*W[n*512+k] + bias[n]; M=16384, N=512, K=512.
// OMODE 1: fp16 out via LDS-transposed coalesced epilogue. OMODE 0: f32 out + res.
template<int OMODE>
__launch_bounds__(256)
__global__ void proj_f16(const unsigned short* __restrict__ A, const unsigned short* __restrict__ W,
                         const float* __restrict__ bias, const float* __restrict__ res,
                         void* __restrict__ outv) {
  __shared__ __align__(16) unsigned short LB[17408];   // staging (16384) + epilogue 128x136
  unsigned short* As = LB;
  unsigned short* Bs = LB + 8192;
  const int m0 = blockIdx.x * 128, n0 = blockIdx.y * 128;
  const int t = threadIdx.x, lane = t & 63, w = t >> 6, wm = w & 1, wn = w >> 1;

  f32x4 acc[4][4];
  #pragma unroll
  for (int i = 0; i < 4; i++)
    #pragma unroll
    for (int j = 0; j < 4; j++) acc[i][j] = (f32x4){0.f, 0.f, 0.f, 0.f};

  for (int k0 = 0; k0 < 512; k0 += 64) {
    __syncthreads();
    #pragma unroll
    for (int fbi = 0; fbi < 4; fbi++) {
      int fb = w * 4 + fbi;
      int row = (fb >> 1) * 16 + (lane & 15);
      int g   = (fb & 1) * 4 + (lane >> 4);
      gl_lds16(A + (long)(m0 + row) * 512 + k0 + g * 8, &As[(fb * 64) << 3]);
      gl_lds16(W + (long)(n0 + row) * 512 + k0 + g * 8, &Bs[(fb * 64) << 3]);
    }
    __syncthreads();
    #pragma unroll
    for (int kk = 0; kk < 2; kk++) {
      f16x8 a[4], b[4];
      #pragma unroll
      for (int i = 0; i < 4; i++)
        a[i] = *(const f16x8*)&As[(((wm * 4 + i) * 2 + kk) * 64 + lane) << 3];
      #pragma unroll
      for (int j = 0; j < 4; j++)
        b[j] = *(const f16x8*)&Bs[(((wn * 4 + j) * 2 + kk) * 64 + lane) << 3];
      #pragma unroll
      for (int i = 0; i < 4; i++)
        #pragma unroll
        for (int j = 0; j < 4; j++)
          acc[i][j] = __builtin_amdgcn_mfma_f32_16x16x32_f16(a[i], b[j], acc[i][j], 0, 0, 0);
    }
  }

  const int lm = lane & 15, quad = lane >> 4;
  if (OMODE == 1) {
    __syncthreads();
    #pragma unroll
    for (int i = 0; i < 4; i++)
      #pragma unroll
      for (int j = 0; j < 4; j++) {
        int rr = wm * 64 + i * 16 + quad * 4;
        int cc = wn * 64 + j * 16 + lm;
        float bb = bias[n0 + cc];
        #pragma unroll
        for (int r = 0; r < 4; r++)
          LB[(rr + r) * 136 + cc] = __half_as_ushort(__float2half(acc[i][j][r] + bb));
      }
    __syncthreads();
    #pragma unroll
    for (int k = 0; k < 8; k++) {
      int ro = k * 16 + (t >> 4), col = (t & 15) * 8;
      uint4 vv = *(const uint4*)&LB[ro * 136 + col];
      *(uint4*)((unsigned short*)outv + (long)(m0 + ro) * 512 + n0 + col) = vv;
    }
  } else {
    #pragma unroll
    for (int i = 0; i < 4; i++)
      #pragma unroll
      for (int j = 0; j < 4; j++) {
        int nn = m0 + wm * 64 + i * 16 + quad * 4;
        int cc = n0 + wn * 64 + j * 16 + lm;
        float bb = bias[cc];
        #pragma unroll
        for (int r = 0; r < 4; r++) {
          long idx = (long)(nn + r) * 512 + cc;
          ((float*)outv)[idx] = acc[i][j][r] + bb + res[idx];
        }
      }
  }
}

// ---------------- Transpose fp16: (512,4096)-view -> [4096][512] ----------------
__global__ void transpose_f16(const unsigned short* __restrict__ qb,
                              const unsigned short* __restrict__ kb,
                              unsigned short* __restrict__ tr) {
  __shared__ __align__(16) unsigned short ld[64 * 72];
  const unsigned short* in = blockIdx.z ? kb : qb;
  unsigned short* o = tr + (blockIdx.z ? 2097152 : 0);
  const int n0 = blockIdx.x * 64, c0 = blockIdx.y * 64;
  const int t = threadIdx.x;
  unsigned* ld32 = (unsigned*)ld;
  {
    const int p = t >> 3, cg = t & 7;
    uint4 r0 = *(const uint4*)(in + (long)(c0 + 2 * p) * 4096 + n0 + 8 * cg);
    uint4 r1 = *(const uint4*)(in + (long)(c0 + 2 * p + 1) * 4096 + n0 + 8 * cg);
    unsigned aw[4] = { r0.x, r0.y, r0.z, r0.w };
    unsigned bw[4] = { r1.x, r1.y, r1.z, r1.w };
    #pragma unroll
    for (int i = 0; i < 4; i++) {
      ld32[(8 * cg + 2 * i) * 36 + p]     = (aw[i] & 0xFFFFu) | (bw[i] << 16);
      ld32[(8 * cg + 2 * i + 1) * 36 + p] = (aw[i] >> 16) | (bw[i] & 0xFFFF0000u);
    }
  }
  __syncthreads();
  {
    const int n = t >> 2, cg2 = t & 3;
    uint4 o0 = *(const uint4*)(ld + n * 72 + 16 * cg2);
    uint4 o1 = *(const uint4*)(ld + n * 72 + 16 * cg2 + 8);
    *(uint4*)(o + (long)(n0 + n) * 512 + c0 + 16 * cg2)     = o0;
    *(uint4*)(o + (long)(n0 + n) * 512 + c0 + 16 * cg2 + 8) = o1;
  }
}

// ---------------- QK^T fp16, full DMA, fp16 S output ----------------
// attn16[n,m] = sum_c qT[n][c]*kT[m][c]; 128x128 tiles, K=512, grid (32,32)
__launch_bounds__(256)
__global__ void qk_f16(const unsigned short* __restrict__ tr, unsigned short* __restrict__ attn) {
  __shared__ __align__(16) unsigned short LB[17408];
  unsigned short* As = LB;
  unsigned short* Bs = LB + 8192;
  const unsigned short* qT = tr;
  const unsigned short* kT = tr + 2097152;
  const int n0 = blockIdx.x * 128, m0 = blockIdx.y * 128;
  const int t = threadIdx.x, lane = t & 63, w = t >> 6, wm = w & 1, wn = w >> 1;

  f32x4 acc[4][4];
  #pragma unroll
  for (int i = 0; i < 4; i++)
    #pragma unroll
    for (int j = 0; j < 4; j++) acc[i][j] = (f32x4){0.f, 0.f, 0.f, 0.f};

  for (int k0 = 0; k0 < 512; k0 += 64) {
    __syncthreads();
    #pragma unroll
    for (int fbi = 0; fbi < 4; fbi++) {
      int fb = w * 4 + fbi;
      int row = (fb >> 1) * 16 + (lane & 15);
      int g   = (fb & 1) * 4 + (lane >> 4);
      gl_lds16(qT + (long)(n0 + row) * 512 + k0 + g * 8, &As[(fb * 64) << 3]);
      gl_lds16(kT + (long)(m0 + row) * 512 + k0 + g * 8, &Bs[(fb * 64) << 3]);
    }
    __syncthreads();
    #pragma unroll
    for (int kk = 0; kk < 2; kk++) {
      f16x8 a[4], b[4];
      #pragma unroll
      for (int i = 0; i < 4; i++)
        a[i] = *(const f16x8*)&As[(((wm * 4 + i) * 2 + kk) * 64 + lane) << 3];
      #pragma unroll
      for (int j = 0; j < 4; j++)
        b[j] = *(const f16x8*)&Bs[(((wn * 4 + j) * 2 + kk) * 64 + lane) << 3];
      #pragma unroll
      for (int i = 0; i < 4; i++)
        #pragma unroll
        for (int j = 0; j < 4; j++)
          acc[i][j] = __builtin_amdgcn_mfma_f32_16x16x32_f16(a[i], b[j], acc[i][j], 0, 0, 0);
    }
  }

  const int lm = lane & 15, quad = lane >> 4;
  __syncthreads();
  #pragma unroll
  for (int i = 0; i < 4; i++)
    #pragma unroll
    for (int j = 0; j < 4; j++) {
      int rr = wm * 64 + i * 16 + quad * 4;
      int cc = wn * 64 + j * 16 + lm;
      #pragma unroll
      for (int r = 0; r < 4; r++)
        LB[(rr + r) * 136 + cc] = __half_as_ushort(__float2half(acc[i][j][r]));
    }
  __syncthreads();
  #pragma unroll
  for (int k = 0; k < 8; k++) {
    int ro = k * 16 + (t >> 4), col = (t & 15) * 8;
    uint4 vv = *(const uint4*)&LB[ro * 136 + col];
    *(uint4*)(attn + (long)(n0 + ro) * 4096 + m0 + col) = vv;
  }
}

// ---------------- Row softmax: fp16 in, fp16 out, in place ----------------
__global__ void softmax_f16ip(unsigned short* __restrict__ attn) {
  unsigned short* p = attn + (long)blockIdx.x * HWDIM;
  const int t = threadIdx.x;                 // 16 shorts per thread
  uint4 u0 = *(const uint4*)(p + t * 16);
  uint4 u1 = *(const uint4*)(p + t * 16 + 8);
  float v[16];
  {
    unsigned uu[8] = { u0.x, u0.y, u0.z, u0.w, u1.x, u1.y, u1.z, u1.w };
    #pragma unroll
    for (int i = 0; i < 8; i++) { float2 f = up2(uu[i]); v[2*i] = f.x; v[2*i+1] = f.y; }
  }
  float mx = -1e30f;
  #pragma unroll
  for (int i = 0; i < 16; i++) mx = fmaxf(mx, v[i]);
  #pragma unroll
  for (int o = 32; o > 0; o >>= 1) mx = fmaxf(mx, __shfl_xor(mx, o, 64));
  __shared__ float rmax[4], rsum[4];
  if ((t & 63) == 0) rmax[t >> 6] = mx;
  __syncthreads();
  mx = fmaxf(fmaxf(rmax[0], rmax[1]), fmaxf(rmax[2], rmax[3]));
  float s = 0.f;
  #pragma unroll
  for (int i = 0; i < 16; i++) { v[i] = __expf(v[i] - mx); s += v[i]; }
  #pragma unroll
  for (int o = 32; o > 0; o >>= 1) s += __shfl_xor(s, o, 64);
  if ((t & 63) == 0) rsum[t >> 6] = s;
  __syncthreads();
  s = (rsum[0] + rsum[1]) + (rsum[2] + rsum[3]);
  float inv = 1.f / s;
  uint4 w0, w1;
  w0.x = pkf16(v[0]*inv,  v[1]*inv);  w0.y = pkf16(v[2]*inv,  v[3]*inv);
  w0.z = pkf16(v[4]*inv,  v[5]*inv);  w0.w = pkf16(v[6]*inv,  v[7]*inv);
  w1.x = pkf16(v[8]*inv,  v[9]*inv);  w1.y = pkf16(v[10]*inv, v[11]*inv);
  w1.z = pkf16(v[12]*inv, v[13]*inv); w1.w = pkf16(v[14]*inv, v[15]*inv);
  *(uint4*)(p + t * 16)     = w0;
  *(uint4*)(p + t * 16 + 8) = w1;
}

// ---------------- PV: fp16 P [4096][4096] x fp16 V, full DMA, split-K 4 ----------------
__launch_bounds__(256)
__global__ void pv_f16(const unsigned short* __restrict__ P, const unsigned short* __restrict__ V,
                       unsigned short* __restrict__ pvp) {
  __shared__ __align__(16) unsigned short LB[17408];
  unsigned short* As = LB;
  unsigned short* Bs = LB + 8192;
  const int n0 = blockIdx.x * 128, c0 = blockIdx.y * 128;
  const long kbase = (long)blockIdx.z * 1024;
  unsigned short* __restrict__ Pout = pvp + (long)blockIdx.z * 2097152;
  const int t = threadIdx.x, lane = t & 63, w = t >> 6, wm = w & 1, wn = w >> 1;

  f32x4 acc[4][4];
  #pragma unroll
  for (int i = 0; i < 4; i++)
    #pragma unroll
    for (int j = 0; j < 4; j++) acc[i][j] = (f32x4){0.f, 0.f, 0.f, 0.f};

  for (int k0 = 0; k0 < 1024; k0 += 64) {
    __syncthreads();
    #pragma unroll
    for (int fbi = 0; fbi < 4; fbi++) {
      int fb = w * 4 + fbi;
      int row = (fb >> 1) * 16 + (lane & 15);
      int g   = (fb & 1) * 4 + (lane >> 4);
      gl_lds16(P + (long)(n0 + row) * 4096 + kbase + k0 + g * 8, &As[(fb * 64) << 3]);
      gl_lds16(V + (long)(c0 + row) * 4096 + kbase + k0 + g * 8, &Bs[(fb * 64) << 3]);
    }
    __syncthreads();
    #pragma unroll
    for (int kk = 0; kk < 2; kk++) {
      f16x8 a[4], b[4];
      #pragma unroll
      for (int i = 0; i < 4; i++)
        a[i] = *(const f16x8*)&As[(((wm * 4 + i) * 2 + kk) * 64 + lane) << 3];
      #pragma unroll
      for (int j = 0; j < 4; j++)
        b[j] = *(const f16x8*)&Bs[(((wn * 4 + j) * 2 + kk) * 64 + lane) << 3];
      #pragma unroll
      for (int i = 0; i < 4; i++)
        #pragma unroll
        for (int j = 0; j < 4; j++)
          acc[i][j] = __builtin_amdgcn_mfma_f32_16x16x32_f16(a[i], b[j], acc[i][j], 0, 0, 0);
    }
  }

  const int lm = lane & 15, quad = lane >> 4;
  __syncthreads();
  #pragma unroll
  for (int i = 0; i < 4; i++)
    #pragma unroll
    for (int j = 0; j < 4; j++) {
      int rr = wm * 64 + i * 16 + quad * 4;
      int cc = wn * 64 + j * 16 + lm;
      #pragma unroll
      for (int r = 0; r < 4; r++)
        LB[(rr + r) * 136 + cc] = __half_as_ushort(__float2half(acc[i][j][r]));
    }
  __syncthreads();
  #pragma unroll
  for (int k = 0; k < 8; k++) {
    int ro = k * 16 + (t >> 4), col = (t & 15) * 8;
    uint4 vv = *(const uint4*)&LB[ro * 136 + col];
    *(uint4*)(Pout + (long)(n0 + ro) * 512 + c0 + col) = vv;
  }
}

// ---------------- sum 4 fp16 partials -> fp16 ot ----------------
__global__ void add4_f16(const unsigned short* __restrict__ p, unsigned short* __restrict__ o) {
  long e = ((long)blockIdx.x * 256 + threadIdx.x) * 4;
  float sx = 0.f, sy = 0.f, sz = 0.f, sw = 0.f;
  #pragma unroll
  for (int z = 0; z < 4; z++) {
    uint2 u = *(const uint2*)(p + (long)z * 2097152 + e);
    float2 f0 = up2(u.x), f1 = up2(u.y);
    sx += f0.x; sy += f0.y; sz += f1.x; sw += f1.y;
  }
  *(uint2*)(o + e) = (uint2){ pkf16(sx, sy), pkf16(sz, sw) };
}

// ---------------- launch ----------------
extern "C" void kernel_launch(void* const* d_in, const int* in_sizes, int n_in,
                              void* d_out, int out_size, void* d_ws, size_t ws_size,
                              hipStream_t stream) {
  (void)in_sizes; (void)n_in; (void)out_size; (void)ws_size;
  const float* x  = (const float*)d_in[0];
  const float* gw = (const float*)d_in[1];
  const float* gb = (const float*)d_in[2];
  const float* wq = (const float*)d_in[3];
  const float* bq = (const float*)d_in[4];
  const float* wk = (const float*)d_in[5];
  const float* bk = (const float*)d_in[6];
  const float* wv = (const float*)d_in[7];
  const float* bv = (const float*)d_in[8];
  const float* wo = (const float*)d_in[9];
  const float* bo = (const float*)d_in[10];
  float* out = (float*)d_out;

  // Workspace (~124 MB, all fp16 except mu/rs):
  //  [attn16 32MB | h 16MB aliases start][qf 16][kf 16][vf 16][tr 8][pvp 16][ot 16][wf 2][mu/rs]
  unsigned short* attn = (unsigned short*)d_ws;
  unsigned short* h    = attn;                 // dead before first qk write
  unsigned short* qf   = attn + 16777216;
  unsigned short* kf   = qf + 8388608;
  unsigned short* vf   = kf + 8388608;
  unsigned short* tr   = vf + 8388608;
  unsigned short* pvp  = tr + 4194304;
  unsigned short* ot   = pvp + 8388608;
  unsigned short* wf   = ot + 8388608;
  float* mu = (float*)(wf + 1048576);
  float* rs = mu + 128;

  gn_stats_kernel<<<dim3(128), dim3(256), 0, stream>>>(x, mu, rs);
  gn_norm_f16<<<dim3(8192), dim3(256), 0, stream>>>(x, mu, rs, gw, gb, h);
  wcvt<<<dim3(256, 4), dim3(256), 0, stream>>>(wq, wk, wv, wo, wf);

  dim3 gproj(128, 4);
  proj_f16<1><<<gproj, 256, 0, stream>>>(h, wf,          bq, nullptr, qf);
  proj_f16<1><<<gproj, 256, 0, stream>>>(h, wf + 262144, bk, nullptr, kf);
  proj_f16<1><<<gproj, 256, 0, stream>>>(h, wf + 524288, bv, nullptr, vf);

  for (int b = 0; b < BATCH; b++) {
    transpose_f16<<<dim3(64, 8, 2), 256, 0, stream>>>(qf + (long)b * CNT, kf + (long)b * CNT, tr);
    qk_f16<<<dim3(32, 32), 256, 0, stream>>>(tr, attn);
    softmax_f16ip<<<dim3(4096), 256, 0, stream>>>(attn);
    pv_f16<<<dim3(32, 4, 4), 256, 0, stream>>>(attn, vf + (long)b * CNT, pvp);
    add4_f16<<<dim3(2048), 256, 0, stream>>>(pvp, ot + (long)b * CNT);
  }
  proj_f16<0><<<gproj, 256, 0, stream>>>(ot, wf + 786432, bo, x, (void*)out);
}